// Round 3
// baseline (144.575 us; speedup 1.0000x reference)
//
#include <hip/hip_runtime.h>
#include <math.h>

#define S_LEN 1024
#define D_DIM 64
#define NBH   16
#define RPB   14
#define NSB   74           // ceil(1024/14)

typedef unsigned short ushort_t;
typedef unsigned int uint_t;
typedef __attribute__((ext_vector_type(8))) _Float16 half8;  // 8 f16 (4 VGPRs)
typedef __attribute__((ext_vector_type(2))) _Float16 h2;
typedef __attribute__((ext_vector_type(4))) short short4v;   // 8 B
typedef __attribute__((ext_vector_type(4))) float f32x4;

__device__ __forceinline__ ushort_t f16bits(float x) {
    _Float16 h = (_Float16)x;                 // RNE
    ushort_t b;
    __builtin_memcpy(&b, &h, 2);
    return b;
}
__device__ __forceinline__ float uniform_f(float x) {
    return __int_as_float(__builtin_amdgcn_readfirstlane(__float_as_int(x)));
}
__device__ __forceinline__ float fast_exp2(float x) {
#if __has_builtin(__builtin_amdgcn_exp2f)
    return __builtin_amdgcn_exp2f(x);         // v_exp_f32 (2^x)
#else
    return exp2f(x);
#endif
}
__device__ __forceinline__ half8 mk8(uint2 a, uint2 b) {
    union { uint_t u[4]; half8 h; } c;
    c.u[0] = a.x; c.u[1] = a.y; c.u[2] = b.x; c.u[3] = b.y;
    return c.h;
}
// dpT swizzle: row = 16 halfs = 4 units of 8B; unit p stored at (p+(row>>2))&3.
// For any 16 consecutive rows the (row%4, row>>2) pairs are bijective ->
// bank-uniform wave-b64 access on both the Phase-A writes and Phase-B reads.
__device__ __forceinline__ int swz(int row, int unit) {
    return (row << 4) + (((unit + (row >> 2)) & 3) << 2);
}

// ------------------------------ Prep ----------------------------------------
// blocks [0,512):    K * 0.125 -> f16 QK B-frag tiled layout (16B stores)
// blocks [512,768):  V transpose -> f16 PV B-frag tiled layout
// blocks [768,1024): mask bit-pack, thread-per-word
// block  1024:       banded conv-weight MFMA A-fragment table (hi/lo split)
__global__ __launch_bounds__(256) void prep(
    const float* __restrict__ k, const float* __restrict__ v,
    const int* __restrict__ mask, const float* __restrict__ conv_w,
    ushort_t* __restrict__ kh, ushort_t* __restrict__ vh,
    unsigned* __restrict__ mw, ushort_t* __restrict__ wtab)
{
    __shared__ float Ls[64][65];
    const int tid = threadIdx.x;
    const int bx = blockIdx.x;
    if (bx < 512) {
        const int gid  = bx * 256 + tid;          // 0..131071
        const int bh   = gid >> 13;
        const int tile = (gid >> 7) & 63;
        const int ch   = (gid >> 6) & 1;
        const int lane = gid & 63;
        const int quad = lane >> 4, t15 = lane & 15;
        const float* src = k + ((size_t)bh * S_LEN + tile * 16 + t15) * D_DIM
                             + ch * 32 + quad * 8;
        float x[8];
        *(float4*)(x + 0) = *(const float4*)(src);
        *(float4*)(x + 4) = *(const float4*)(src + 4);
        ushort_t hv[8];
        #pragma unroll
        for (int i = 0; i < 8; ++i) hv[i] = f16bits(x[i] * 0.125f);
        *(short4v*)(kh + (size_t)gid * 8)     = *(short4v*)(hv);
        *(short4v*)(kh + (size_t)gid * 8 + 4) = *(short4v*)(hv + 4);
    } else if (bx < 768) {
        const int bi = bx - 512;
        const int tt = bi & 15, bh = bi >> 4;
        const float* vb = v + ((size_t)bh * S_LEN + tt * 64) * D_DIM;
        #pragma unroll
        for (int p = 0; p < 4; ++p) {
            int idx = p * 1024 + tid * 4;
            int r = idx >> 6, c = idx & 63;
            float4 x = *(const float4*)(vb + r * 64 + c);
            Ls[r][c] = x.x; Ls[r][c+1] = x.y; Ls[r][c+2] = x.z; Ls[r][c+3] = x.w;
        }
        __syncthreads();
        const int d = tid >> 2, c0 = (tid & 3) * 16;
        ushort_t hi[16];
        #pragma unroll
        for (int j = 0; j < 16; ++j) hi[j] = f16bits(Ls[c0 + j][d]);
        const int tb0 = tt * 8 + (c0 >> 3);
        const size_t o0 = (((size_t)bh * 128 + tb0) * 64 + d) * 8;
        const size_t o1 = (((size_t)bh * 128 + tb0 + 1) * 64 + d) * 8;
        *(short4v*)(vh + o0)     = *(short4v*)(hi);
        *(short4v*)(vh + o0 + 4) = *(short4v*)(hi + 4);
        *(short4v*)(vh + o1)     = *(short4v*)(hi + 8);
        *(short4v*)(vh + o1 + 4) = *(short4v*)(hi + 12);
    } else if (bx < 1024) {
        const int gid = (bx - 768) * 256 + tid;    // 0..65535
        const int row = gid >> 5, wd = gid & 31;   // row = b*1024+s
        const int4* mp = (const int4*)(mask + (size_t)row * 1024 + wd * 32);
        unsigned bits = 0;
        #pragma unroll
        for (int p = 0; p < 8; ++p) {
            int4 qv = mp[p];
            bits |= (qv.x != 0 ? 1u : 0u) << (p * 4 + 0);
            bits |= (qv.y != 0 ? 1u : 0u) << (p * 4 + 1);
            bits |= (qv.z != 0 ? 1u : 0u) << (p * 4 + 2);
            bits |= (qv.w != 0 ? 1u : 0u) << (p * 4 + 3);
        }
        mw[(size_t)row * 32 + wd] = bits;
    } else {
        // A-fragment weight table: frag g in {0: dc0hi|dc1hi, 1: dc0lo|dc1lo,
        // 2: dc2hi|dc2lo}; lane l holds A[row=l&15][k=(l>>4)*8+i];
        // A_dc[o][r] = w[r-o+1][dc] if |r-o|<=1 else 0 (k<16: r=k; k>=16: r=k-16)
        if (tid < 64) {
            const int o = tid & 15, qd = tid >> 4;
            half8* wt = (half8*)wtab;
            #pragma unroll
            for (int f = 0; f < 4; ++f) {
                half8 fr0 = {}, fr1 = {}, fr2 = {};
                #pragma unroll
                for (int i = 0; i < 8; ++i) {
                    const int kk = qd * 8 + i;
                    const int r  = kk & 15;
                    const bool hiK = kk < 16;
                    #pragma unroll
                    for (int dr = 0; dr < 3; ++dr) {
                        if (r - o == dr - 1) {
                            const float w0 = conv_w[f*9 + dr*3 + 0];
                            const float w1 = conv_w[f*9 + dr*3 + 1];
                            const float w2 = conv_w[f*9 + dr*3 + 2];
                            const _Float16 w0h = (_Float16)w0;
                            const _Float16 w1h = (_Float16)w1;
                            const _Float16 w2h = (_Float16)w2;
                            const _Float16 w0l = (_Float16)(w0 - (float)w0h);
                            const _Float16 w1l = (_Float16)(w1 - (float)w1h);
                            const _Float16 w2l = (_Float16)(w2 - (float)w2h);
                            fr0[i] = hiK ? w0h : w1h;
                            fr1[i] = hiK ? w0l : w1l;
                            fr2[i] = hiK ? w2h : w2l;
                        }
                    }
                }
                wt[(f*3 + 0) * 64 + tid] = fr0;
                wt[(f*3 + 1) * 64 + tid] = fr1;
                wt[(f*3 + 2) * 64 + tid] = fr2;
            }
        }
    }
}

// ---------- Fused: QK^T -> MFMA conv -> PV ----------------------------------
// grid (74 s-tiles, 16 bh), block 512 = 8 waves. LDS 39.5 KB -> 4 blocks/CU;
// __launch_bounds__(512,8) caps VGPR at 64 -> 8 waves/SIMD static occupancy.
// Phase A: QK MFMA; dp TRANSPOSED into swizzled stride-16 sBuf (b64 writes).
// Phase B: conv as banded matmul on MFMA pipe, tile-PAIR outer loop
//          (B-frags for 2 tiles read once), NON-UNROLLED filter loop reloads
//          the 3 weight frags of filter f from L1-resident wtab each pass
//          (blocks load-CSE -> bounded VGPR). Per-filter partial epilogue
//          pre += aF*y + bF*|y| is order-equivalent to computing all 4 accs.
// Phase C: P written in place row-major (PSTR 1032, 16B-aligned b128 reads);
//          PV + all-ones rowsum MFMA; th-halves merged via oBuf/lsRow.
#define PSTR 1032
__global__ __launch_bounds__(512, 8) void fused_qk_conv_av(
    const float* __restrict__ q,
    const ushort_t* __restrict__ kh, const unsigned* __restrict__ mw,
    const ushort_t* __restrict__ vh, const ushort_t* __restrict__ wtab,
    const float* __restrict__ conv_b,
    const float* __restrict__ lin_w, const float* __restrict__ lin_b,
    float* __restrict__ out)
{
    __shared__ ushort_t sBuf[16512];           // 33.0 KB; dpT in A/B, P in C
    __shared__ float oBuf[16][68];             // 4.35 KB
    __shared__ float lsRow[16];                // 64 B
    __shared__ unsigned mbT[32][16];           // 2 KB (mask words, transposed)

    const int st = blockIdx.x, bh = blockIdx.y;
    const int s0 = st * RPB;
    const int b  = bh >> 3;
    const int tid = threadIdx.x;
    const int wave = tid >> 6, lane = tid & 63;
    const int m = lane & 15, quad = lane >> 4;

    // mask bits -> transposed LDS: mbT[word][row o]
    {
        const int wd = tid >> 4, o = tid & 15;
        const int s = s0 - 1 + o;
        mbT[wd][o] = (s >= 0 && s < S_LEN)
                   ? mw[((size_t)b * S_LEN + s) * 32 + wd] : 0u;
    }
    // zero dpT pad rows: row 1 (col -1) and row 1026 (col 1024) — full rows,
    // so the unit swizzle is irrelevant here.
    if (tid < 32) {
        const int row = (tid < 16) ? 1 : 1026;
        sBuf[(row << 4) + (tid & 15)] = 0;
    }

    // ---------------- Phase A: QK into LDS, transposed+swizzled -------------
    const int sA = s0 - 1 + m;
    const int sQ = sA < 0 ? 0 : (sA > S_LEN - 1 ? S_LEN - 1 : sA);
    const float* qp = q + ((size_t)bh * S_LEN + sQ) * D_DIM + quad * 8;
    float qa[16];
    *(float4*)(qa + 0)  = *(const float4*)(qp + 0);
    *(float4*)(qa + 4)  = *(const float4*)(qp + 4);
    *(float4*)(qa + 8)  = *(const float4*)(qp + 32);
    *(float4*)(qa + 12) = *(const float4*)(qp + 36);
    half8 AH0, AH1;
    #pragma unroll
    for (int i = 0; i < 8; ++i) {
        AH0[i] = (_Float16)qa[i];          // 1/8 scale folded into kh
        AH1[i] = (_Float16)qa[8 + i];
    }

    #pragma unroll
    for (int tt = 0; tt < 8; ++tt) {
        const int tile = wave * 8 + tt;
        const size_t kb = (((size_t)bh * 64 + tile) * 128 + lane) * 8;
        half8 KH0 = *(const half8*)(kh + kb);
        half8 KH1 = *(const half8*)(kh + kb + 512);
        f32x4 a = {0.f, 0.f, 0.f, 0.f};
        a = __builtin_amdgcn_mfma_f32_16x16x32_f16(AH0, KH0, a, 0, 0, 0);
        a = __builtin_amdgcn_mfma_f32_16x16x32_f16(AH1, KH1, a, 0, 0, 0);
        // C: row = quad*4+r (s-row), col = tile*16+m -> dpT[col+2][quad*4..+3]
        ushort_t t4[4];
        #pragma unroll
        for (int r = 0; r < 4; ++r) {
            const int s = s0 - 1 + quad * 4 + r;
            const float v = (s >= 0 && s < S_LEN) ? a[r] : 0.f;
            t4[r] = f16bits(v);
        }
        uint2 wv2;
        wv2.x = (uint_t)t4[0] | ((uint_t)t4[1] << 16);
        wv2.y = (uint_t)t4[2] | ((uint_t)t4[3] << 16);
        *(uint2*)&sBuf[swz(tile * 16 + m + 2, quad)] = wv2;
    }

    const float L2E = 1.44269504088896341f;
    const float lbE = uniform_f(lin_b[0] * L2E);

    __syncthreads();

    // ---------------- Phase B: MFMA conv + mask + exp2 ----------------------
    // B01[k][n=m]: k<16 -> dc0 (sBuf row c+1), k>=16 -> dc1 (row c+2);
    //   lane: row = tile*16 + m + 1 + (quad>>1), units 2*(quad&1), +1
    // B22: dc2 (row c+3) duplicated in both k-halves; same units.
    const int u0 = (quad & 1) << 1;
    const int rB = m + 1 + (quad >> 1);
    uint_t Ps[16];            // packed f16 P: 2 words per tile
    #pragma unroll
    for (int p = 0; p < 4; ++p) {
        const int tileA = wave * 8 + p * 2;      // even tile of the pair
        const int baseA = tileA * 16;
        // B fragments for both tiles of the pair (read once, reused 4x)
        half8 BA01 = mk8(*(const uint2*)&sBuf[swz(baseA + rB, u0)],
                         *(const uint2*)&sBuf[swz(baseA + rB, u0 + 1)]);
        half8 BA22 = mk8(*(const uint2*)&sBuf[swz(baseA + m + 3, u0)],
                         *(const uint2*)&sBuf[swz(baseA + m + 3, u0 + 1)]);
        half8 BB01 = mk8(*(const uint2*)&sBuf[swz(baseA + 16 + rB, u0)],
                         *(const uint2*)&sBuf[swz(baseA + 16 + rB, u0 + 1)]);
        half8 BB22 = mk8(*(const uint2*)&sBuf[swz(baseA + 16 + m + 3, u0)],
                         *(const uint2*)&sBuf[swz(baseA + 16 + m + 3, u0 + 1)]);
        float preA[4], preB[4];
        #pragma unroll
        for (int r = 0; r < 4; ++r) { preA[r] = lbE; preB[r] = lbE; }
        // filter loop NOT unrolled: weight frags reloaded from L1 each pass,
        // keeping peak VGPR bounded (no cross-iteration load CSE possible).
        #pragma unroll 1
        for (int f = 0; f < 4; ++f) {
            const half8* wp = (const half8*)wtab + f * 192 + lane;
            const half8 W0 = wp[0];
            const half8 W1 = wp[64];
            const half8 W2 = wp[128];
            const float cbf = conv_b[f];
            const float lwf = lin_w[f];
            const float af  = uniform_f(0.505f * lwf * L2E);
            const float bf2 = uniform_f(0.495f * lwf * L2E);
            f32x4 aA = {cbf, cbf, cbf, cbf};
            f32x4 aB = {cbf, cbf, cbf, cbf};
            aA = __builtin_amdgcn_mfma_f32_16x16x32_f16(W0, BA01, aA, 0, 0, 0);
            aB = __builtin_amdgcn_mfma_f32_16x16x32_f16(W0, BB01, aB, 0, 0, 0);
            aA = __builtin_amdgcn_mfma_f32_16x16x32_f16(W1, BA01, aA, 0, 0, 0);
            aB = __builtin_amdgcn_mfma_f32_16x16x32_f16(W1, BB01, aB, 0, 0, 0);
            aA = __builtin_amdgcn_mfma_f32_16x16x32_f16(W2, BA22, aA, 0, 0, 0);
            aB = __builtin_amdgcn_mfma_f32_16x16x32_f16(W2, BB22, aB, 0, 0, 0);
            #pragma unroll
            for (int r = 0; r < 4; ++r) {
                const float yA = aA[r], yB = aB[r];
                preA[r] = fmaf(af, yA, preA[r]);
                preA[r] = fmaf(bf2, fabsf(yA), preA[r]);  // abs = VOP3 modifier
                preB[r] = fmaf(af, yB, preB[r]);
                preB[r] = fmaf(bf2, fabsf(yB), preB[r]);
            }
        }
        // epilogue: C layout row = quad*4+r, col = tile*16+m
        const uint4 mq = *(const uint4*)&mbT[(tileA >> 1)][quad * 4];
        float pvA[4], pvB[4];
        #pragma unroll
        for (int r = 0; r < 4; ++r) {
            const int o = quad * 4 + r;
            const bool act = (o >= 1) && (o <= RPB) && (s0 - 1 + o < S_LEN);
            const unsigned mword = (r == 0) ? mq.x : (r == 1) ? mq.y
                                 : (r == 2) ? mq.z : mq.w;
            const bool kA = act && ((mword >> m) & 1u);
            const bool kB = act && ((mword >> (16 + m)) & 1u);
            pvA[r] = fast_exp2(kA ? preA[r] : -1e30f);
            pvB[r] = fast_exp2(kB ? preB[r] : -1e30f);
        }
        Ps[p*4 + 0] = (uint_t)f16bits(pvA[0]) | ((uint_t)f16bits(pvA[1]) << 16);
        Ps[p*4 + 1] = (uint_t)f16bits(pvA[2]) | ((uint_t)f16bits(pvA[3]) << 16);
        Ps[p*4 + 2] = (uint_t)f16bits(pvB[0]) | ((uint_t)f16bits(pvB[1]) << 16);
        Ps[p*4 + 3] = (uint_t)f16bits(pvB[2]) | ((uint_t)f16bits(pvB[3]) << 16);
    }
    __syncthreads();   // all dpT reads done -> safe to overwrite with P

    // write P row-major over sBuf: P[o][t] at sBuf[o*PSTR + t]
    #pragma unroll
    for (int tt = 0; tt < 8; ++tt) {
        const int c = (wave * 8 + tt) * 16 + m;
        ushort_t* pp = &sBuf[quad * 4 * PSTR + c];
        const uint_t lo = Ps[2*tt], hi = Ps[2*tt + 1];
        pp[0]        = (ushort_t)lo;
        pp[PSTR]     = (ushort_t)(lo >> 16);
        pp[2*PSTR]   = (ushort_t)hi;
        pp[3*PSTR]   = (ushort_t)(hi >> 16);
    }
    __syncthreads();

    // ---------------- Phase C: PV + MFMA row sums ---------------------------
    const int d0 = (wave & 3) * 16;
    const int th = wave >> 2;
    f32x4 O  = {0.f, 0.f, 0.f, 0.f};
    f32x4 RS = {0.f, 0.f, 0.f, 0.f};
    half8 ONE;
    #pragma unroll
    for (int i = 0; i < 8; ++i) ONE[i] = (_Float16)1.0f;
    const ushort_t* ph_base = &sBuf[m * PSTR + th * 512 + quad * 8];
    const ushort_t* vv_base = vh + ((size_t)bh * 65536
                                    + (size_t)(th * 64 + quad) * 512
                                    + (size_t)(d0 + m) * 8);
    #pragma unroll 4
    for (int i = 0; i < 16; ++i) {
        half8 ph = *(const half8*)(ph_base + i * 32);
        half8 vv = *(const half8*)(vv_base + (size_t)i * 2048);
        O  = __builtin_amdgcn_mfma_f32_16x16x32_f16(ph, vv, O, 0, 0, 0);
        RS = __builtin_amdgcn_mfma_f32_16x16x32_f16(ph, ONE, RS, 0, 0, 0);
    }
    if (wave < 4) {
        #pragma unroll
        for (int r = 0; r < 4; ++r) oBuf[quad * 4 + r][d0 + m] = O[r];
    }
    if (wave == 0 && m == 0) {   // lanes 0,16,32,48: publish th=0 partials
        #pragma unroll
        for (int r = 0; r < 4; ++r) lsRow[quad * 4 + r] = RS[r];
    }
    __syncthreads();
    if (wave >= 4) {
        #pragma unroll
        for (int r = 0; r < 4; ++r) {
            const int br = quad * 4 + r;
            const int s = s0 - 1 + br;
            if (br >= 1 && br <= RPB && s < S_LEN) {
                const float lsum = lsRow[br] + RS[r];
                out[((size_t)bh * S_LEN + s) * D_DIM + d0 + m] =
                    (O[r] + oBuf[br][d0 + m]) / lsum;
            }
        }
    }
}

extern "C" void kernel_launch(void* const* d_in, const int* in_sizes, int n_in,
                              void* d_out, int out_size, void* d_ws, size_t ws_size,
                              hipStream_t stream) {
    const float* q      = (const float*)d_in[0];
    const float* k      = (const float*)d_in[1];
    const float* v      = (const float*)d_in[2];
    const int*   mask   = (const int*)d_in[3];
    const float* conv_w = (const float*)d_in[4];
    const float* conv_b = (const float*)d_in[5];
    const float* lin_w  = (const float*)d_in[6];
    const float* lin_b  = (const float*)d_in[7];
    float* out = (float*)d_out;

    char* wsb = (char*)d_ws;
    const size_t MB = 1024 * 1024;
    ushort_t* kh   = (ushort_t*)(wsb + 0 * MB);          // 2 MiB
    ushort_t* vh   = (ushort_t*)(wsb + 2 * MB);          // 2 MiB
    unsigned* mw   = (unsigned*)(wsb + 4 * MB);          // 256 KiB
    ushort_t* wtab = (ushort_t*)(wsb + 4 * MB + 256 * 1024);  // 12 KiB

    prep<<<dim3(1025), 256, 0, stream>>>(k, v, mask, conv_w, kh, vh, mw, wtab);
    fused_qk_conv_av<<<dim3(NSB, NBH), 512, 0, stream>>>(
        q, kh, mw, vh, wtab, conv_b, lin_w, lin_b, out);
}

// Round 4
// 124.829 us; speedup vs baseline: 1.1582x; 1.1582x over previous
//
#include <hip/hip_runtime.h>
#include <math.h>

#define S_LEN 1024
#define D_DIM 64
#define NBH   16
#define RPB   14
#define NSB   74           // ceil(1024/14)

typedef unsigned short ushort_t;
typedef unsigned int uint_t;
typedef __attribute__((ext_vector_type(8))) _Float16 half8;  // 8 f16 (4 VGPRs)
typedef __attribute__((ext_vector_type(2))) _Float16 h2;
typedef __attribute__((ext_vector_type(4))) short short4v;   // 8 B
typedef __attribute__((ext_vector_type(4))) float f32x4;

__device__ __forceinline__ ushort_t f16bits(float x) {
    _Float16 h = (_Float16)x;                 // RNE
    ushort_t b;
    __builtin_memcpy(&b, &h, 2);
    return b;
}
__device__ __forceinline__ float uniform_f(float x) {
    return __int_as_float(__builtin_amdgcn_readfirstlane(__float_as_int(x)));
}
__device__ __forceinline__ float fast_exp2(float x) {
#if __has_builtin(__builtin_amdgcn_exp2f)
    return __builtin_amdgcn_exp2f(x);         // v_exp_f32 (2^x)
#else
    return exp2f(x);
#endif
}
__device__ __forceinline__ half8 mk8(uint2 a, uint2 b) {
    union { uint_t u[4]; half8 h; } c;
    c.u[0] = a.x; c.u[1] = a.y; c.u[2] = b.x; c.u[3] = b.y;
    return c.h;
}
// dpT swizzle: row = 16 halfs = 4 units of 8B; unit p stored at (p+(row>>2))&3.
// For any 16 consecutive rows the (row%4, row>>2) pairs are bijective ->
// bank-uniform wave-b64 access on both the Phase-A writes and Phase-B reads.
__device__ __forceinline__ int swz(int row, int unit) {
    return (row << 4) + (((unit + (row >> 2)) & 3) << 2);
}

// ------------------------------ Prep ----------------------------------------
// blocks [0,512):    K * 0.125 -> f16 QK B-frag tiled layout (16B stores)
// blocks [512,768):  V transpose -> f16 PV B-frag tiled layout
// blocks [768,1024): mask bit-pack, thread-per-word
// block  1024:       banded conv-weight MFMA A-fragment table (hi/lo split)
__global__ __launch_bounds__(256) void prep(
    const float* __restrict__ k, const float* __restrict__ v,
    const int* __restrict__ mask, const float* __restrict__ conv_w,
    ushort_t* __restrict__ kh, ushort_t* __restrict__ vh,
    unsigned* __restrict__ mw, ushort_t* __restrict__ wtab)
{
    __shared__ float Ls[64][65];
    const int tid = threadIdx.x;
    const int bx = blockIdx.x;
    if (bx < 512) {
        const int gid  = bx * 256 + tid;          // 0..131071
        const int bh   = gid >> 13;
        const int tile = (gid >> 7) & 63;
        const int ch   = (gid >> 6) & 1;
        const int lane = gid & 63;
        const int quad = lane >> 4, t15 = lane & 15;
        const float* src = k + ((size_t)bh * S_LEN + tile * 16 + t15) * D_DIM
                             + ch * 32 + quad * 8;
        float x[8];
        *(float4*)(x + 0) = *(const float4*)(src);
        *(float4*)(x + 4) = *(const float4*)(src + 4);
        ushort_t hv[8];
        #pragma unroll
        for (int i = 0; i < 8; ++i) hv[i] = f16bits(x[i] * 0.125f);
        *(short4v*)(kh + (size_t)gid * 8)     = *(short4v*)(hv);
        *(short4v*)(kh + (size_t)gid * 8 + 4) = *(short4v*)(hv + 4);
    } else if (bx < 768) {
        const int bi = bx - 512;
        const int tt = bi & 15, bh = bi >> 4;
        const float* vb = v + ((size_t)bh * S_LEN + tt * 64) * D_DIM;
        #pragma unroll
        for (int p = 0; p < 4; ++p) {
            int idx = p * 1024 + tid * 4;
            int r = idx >> 6, c = idx & 63;
            float4 x = *(const float4*)(vb + r * 64 + c);
            Ls[r][c] = x.x; Ls[r][c+1] = x.y; Ls[r][c+2] = x.z; Ls[r][c+3] = x.w;
        }
        __syncthreads();
        const int d = tid >> 2, c0 = (tid & 3) * 16;
        ushort_t hi[16];
        #pragma unroll
        for (int j = 0; j < 16; ++j) hi[j] = f16bits(Ls[c0 + j][d]);
        const int tb0 = tt * 8 + (c0 >> 3);
        const size_t o0 = (((size_t)bh * 128 + tb0) * 64 + d) * 8;
        const size_t o1 = (((size_t)bh * 128 + tb0 + 1) * 64 + d) * 8;
        *(short4v*)(vh + o0)     = *(short4v*)(hi);
        *(short4v*)(vh + o0 + 4) = *(short4v*)(hi + 4);
        *(short4v*)(vh + o1)     = *(short4v*)(hi + 8);
        *(short4v*)(vh + o1 + 4) = *(short4v*)(hi + 12);
    } else if (bx < 1024) {
        const int gid = (bx - 768) * 256 + tid;    // 0..65535
        const int row = gid >> 5, wd = gid & 31;   // row = b*1024+s
        const int4* mp = (const int4*)(mask + (size_t)row * 1024 + wd * 32);
        unsigned bits = 0;
        #pragma unroll
        for (int p = 0; p < 8; ++p) {
            int4 qv = mp[p];
            bits |= (qv.x != 0 ? 1u : 0u) << (p * 4 + 0);
            bits |= (qv.y != 0 ? 1u : 0u) << (p * 4 + 1);
            bits |= (qv.z != 0 ? 1u : 0u) << (p * 4 + 2);
            bits |= (qv.w != 0 ? 1u : 0u) << (p * 4 + 3);
        }
        mw[(size_t)row * 32 + wd] = bits;
    } else {
        // A-fragment weight table: frag g in {0: dc0hi|dc1hi, 1: dc0lo|dc1lo,
        // 2: dc2hi|dc2lo}; lane l holds A[row=l&15][k=(l>>4)*8+i];
        // A_dc[o][r] = w[r-o+1][dc] if |r-o|<=1 else 0 (k<16: r=k; k>=16: r=k-16)
        if (tid < 64) {
            const int o = tid & 15, qd = tid >> 4;
            half8* wt = (half8*)wtab;
            #pragma unroll
            for (int f = 0; f < 4; ++f) {
                half8 fr0 = {}, fr1 = {}, fr2 = {};
                #pragma unroll
                for (int i = 0; i < 8; ++i) {
                    const int kk = qd * 8 + i;
                    const int r  = kk & 15;
                    const bool hiK = kk < 16;
                    #pragma unroll
                    for (int dr = 0; dr < 3; ++dr) {
                        if (r - o == dr - 1) {
                            const float w0 = conv_w[f*9 + dr*3 + 0];
                            const float w1 = conv_w[f*9 + dr*3 + 1];
                            const float w2 = conv_w[f*9 + dr*3 + 2];
                            const _Float16 w0h = (_Float16)w0;
                            const _Float16 w1h = (_Float16)w1;
                            const _Float16 w2h = (_Float16)w2;
                            const _Float16 w0l = (_Float16)(w0 - (float)w0h);
                            const _Float16 w1l = (_Float16)(w1 - (float)w1h);
                            const _Float16 w2l = (_Float16)(w2 - (float)w2h);
                            fr0[i] = hiK ? w0h : w1h;
                            fr1[i] = hiK ? w0l : w1l;
                            fr2[i] = hiK ? w2h : w2l;
                        }
                    }
                }
                wt[(f*3 + 0) * 64 + tid] = fr0;
                wt[(f*3 + 1) * 64 + tid] = fr1;
                wt[(f*3 + 2) * 64 + tid] = fr2;
            }
        }
    }
}

// ---------- Fused: QK^T -> MFMA conv -> PV ----------------------------------
// grid (74 s-tiles, 16 bh), block 512 = 8 waves. LDS 39.5 KB.
// __launch_bounds__ 2nd arg is min BLOCKS/CU (CUDA semantics — R3 post-mortem:
// (512,8) forced 64 waves/CU -> VGPR 32 -> massive scratch spill). (512,3)
// => 24 waves/CU => VGPR cap 85; natural allocation ~80 fits without spill.
// Phase A: QK MFMA; dp TRANSPOSED into swizzled stride-16 sBuf (b64 writes).
// Phase B: conv as banded matmul on MFMA pipe, tile-PAIR outer loop
//          (B-frags for 2 tiles read once), NON-UNROLLED filter loop reloads
//          the 3 weight frags of filter f from L1-resident wtab each pass
//          (blocks load-CSE -> bounded VGPR). Per-filter partial epilogue
//          pre += aF*y + bF*|y| is order-equivalent to computing all 4 accs.
// Phase C: P written in place row-major (PSTR 1032, 16B-aligned b128 reads);
//          PV + all-ones rowsum MFMA; th-halves merged via oBuf/lsRow.
#define PSTR 1032
__global__ __launch_bounds__(512, 3) void fused_qk_conv_av(
    const float* __restrict__ q,
    const ushort_t* __restrict__ kh, const unsigned* __restrict__ mw,
    const ushort_t* __restrict__ vh, const ushort_t* __restrict__ wtab,
    const float* __restrict__ conv_b,
    const float* __restrict__ lin_w, const float* __restrict__ lin_b,
    float* __restrict__ out)
{
    __shared__ ushort_t sBuf[16512];           // 33.0 KB; dpT in A/B, P in C
    __shared__ float oBuf[16][68];             // 4.35 KB
    __shared__ float lsRow[16];                // 64 B
    __shared__ unsigned mbT[32][16];           // 2 KB (mask words, transposed)

    const int st = blockIdx.x, bh = blockIdx.y;
    const int s0 = st * RPB;
    const int b  = bh >> 3;
    const int tid = threadIdx.x;
    const int wave = tid >> 6, lane = tid & 63;
    const int m = lane & 15, quad = lane >> 4;

    // mask bits -> transposed LDS: mbT[word][row o]
    {
        const int wd = tid >> 4, o = tid & 15;
        const int s = s0 - 1 + o;
        mbT[wd][o] = (s >= 0 && s < S_LEN)
                   ? mw[((size_t)b * S_LEN + s) * 32 + wd] : 0u;
    }
    // zero dpT pad rows: row 1 (col -1) and row 1026 (col 1024) — full rows,
    // so the unit swizzle is irrelevant here.
    if (tid < 32) {
        const int row = (tid < 16) ? 1 : 1026;
        sBuf[(row << 4) + (tid & 15)] = 0;
    }

    // ---------------- Phase A: QK into LDS, transposed+swizzled -------------
    const int sA = s0 - 1 + m;
    const int sQ = sA < 0 ? 0 : (sA > S_LEN - 1 ? S_LEN - 1 : sA);
    const float* qp = q + ((size_t)bh * S_LEN + sQ) * D_DIM + quad * 8;
    float qa[16];
    *(float4*)(qa + 0)  = *(const float4*)(qp + 0);
    *(float4*)(qa + 4)  = *(const float4*)(qp + 4);
    *(float4*)(qa + 8)  = *(const float4*)(qp + 32);
    *(float4*)(qa + 12) = *(const float4*)(qp + 36);
    half8 AH0, AH1;
    #pragma unroll
    for (int i = 0; i < 8; ++i) {
        AH0[i] = (_Float16)qa[i];          // 1/8 scale folded into kh
        AH1[i] = (_Float16)qa[8 + i];
    }

    #pragma unroll
    for (int tt = 0; tt < 8; ++tt) {
        const int tile = wave * 8 + tt;
        const size_t kb = (((size_t)bh * 64 + tile) * 128 + lane) * 8;
        half8 KH0 = *(const half8*)(kh + kb);
        half8 KH1 = *(const half8*)(kh + kb + 512);
        f32x4 a = {0.f, 0.f, 0.f, 0.f};
        a = __builtin_amdgcn_mfma_f32_16x16x32_f16(AH0, KH0, a, 0, 0, 0);
        a = __builtin_amdgcn_mfma_f32_16x16x32_f16(AH1, KH1, a, 0, 0, 0);
        // C: row = quad*4+r (s-row), col = tile*16+m -> dpT[col+2][quad*4..+3]
        ushort_t t4[4];
        #pragma unroll
        for (int r = 0; r < 4; ++r) {
            const int s = s0 - 1 + quad * 4 + r;
            const float v = (s >= 0 && s < S_LEN) ? a[r] : 0.f;
            t4[r] = f16bits(v);
        }
        uint2 wv2;
        wv2.x = (uint_t)t4[0] | ((uint_t)t4[1] << 16);
        wv2.y = (uint_t)t4[2] | ((uint_t)t4[3] << 16);
        *(uint2*)&sBuf[swz(tile * 16 + m + 2, quad)] = wv2;
    }

    const float L2E = 1.44269504088896341f;
    const float lbE = uniform_f(lin_b[0] * L2E);

    __syncthreads();

    // ---------------- Phase B: MFMA conv + mask + exp2 ----------------------
    // B01[k][n=m]: k<16 -> dc0 (sBuf row c+1), k>=16 -> dc1 (row c+2);
    //   lane: row = tile*16 + m + 1 + (quad>>1), units 2*(quad&1), +1
    // B22: dc2 (row c+3) duplicated in both k-halves; same units.
    const int u0 = (quad & 1) << 1;
    const int rB = m + 1 + (quad >> 1);
    uint_t Ps[16];            // packed f16 P: 2 words per tile
    #pragma unroll
    for (int p = 0; p < 4; ++p) {
        const int tileA = wave * 8 + p * 2;      // even tile of the pair
        const int baseA = tileA * 16;
        // B fragments for both tiles of the pair (read once, reused 4x)
        half8 BA01 = mk8(*(const uint2*)&sBuf[swz(baseA + rB, u0)],
                         *(const uint2*)&sBuf[swz(baseA + rB, u0 + 1)]);
        half8 BA22 = mk8(*(const uint2*)&sBuf[swz(baseA + m + 3, u0)],
                         *(const uint2*)&sBuf[swz(baseA + m + 3, u0 + 1)]);
        half8 BB01 = mk8(*(const uint2*)&sBuf[swz(baseA + 16 + rB, u0)],
                         *(const uint2*)&sBuf[swz(baseA + 16 + rB, u0 + 1)]);
        half8 BB22 = mk8(*(const uint2*)&sBuf[swz(baseA + 16 + m + 3, u0)],
                         *(const uint2*)&sBuf[swz(baseA + 16 + m + 3, u0 + 1)]);
        float preA[4], preB[4];
        #pragma unroll
        for (int r = 0; r < 4; ++r) { preA[r] = lbE; preB[r] = lbE; }
        // filter loop NOT unrolled: weight frags reloaded from L1 each pass,
        // keeping peak VGPR bounded (no cross-iteration load CSE possible).
        #pragma unroll 1
        for (int f = 0; f < 4; ++f) {
            const half8* wp = (const half8*)wtab + f * 192 + lane;
            const half8 W0 = wp[0];
            const half8 W1 = wp[64];
            const half8 W2 = wp[128];
            const float cbf = conv_b[f];
            const float lwf = lin_w[f];
            const float af  = uniform_f(0.505f * lwf * L2E);
            const float bf2 = uniform_f(0.495f * lwf * L2E);
            f32x4 aA = {cbf, cbf, cbf, cbf};
            f32x4 aB = {cbf, cbf, cbf, cbf};
            aA = __builtin_amdgcn_mfma_f32_16x16x32_f16(W0, BA01, aA, 0, 0, 0);
            aB = __builtin_amdgcn_mfma_f32_16x16x32_f16(W0, BB01, aB, 0, 0, 0);
            aA = __builtin_amdgcn_mfma_f32_16x16x32_f16(W1, BA01, aA, 0, 0, 0);
            aB = __builtin_amdgcn_mfma_f32_16x16x32_f16(W1, BB01, aB, 0, 0, 0);
            aA = __builtin_amdgcn_mfma_f32_16x16x32_f16(W2, BA22, aA, 0, 0, 0);
            aB = __builtin_amdgcn_mfma_f32_16x16x32_f16(W2, BB22, aB, 0, 0, 0);
            #pragma unroll
            for (int r = 0; r < 4; ++r) {
                const float yA = aA[r], yB = aB[r];
                preA[r] = fmaf(af, yA, preA[r]);
                preA[r] = fmaf(bf2, fabsf(yA), preA[r]);  // abs = VOP3 modifier
                preB[r] = fmaf(af, yB, preB[r]);
                preB[r] = fmaf(bf2, fabsf(yB), preB[r]);
            }
        }
        // epilogue: C layout row = quad*4+r, col = tile*16+m
        const uint4 mq = *(const uint4*)&mbT[(tileA >> 1)][quad * 4];
        float pvA[4], pvB[4];
        #pragma unroll
        for (int r = 0; r < 4; ++r) {
            const int o = quad * 4 + r;
            const bool act = (o >= 1) && (o <= RPB) && (s0 - 1 + o < S_LEN);
            const unsigned mword = (r == 0) ? mq.x : (r == 1) ? mq.y
                                 : (r == 2) ? mq.z : mq.w;
            const bool kA = act && ((mword >> m) & 1u);
            const bool kB = act && ((mword >> (16 + m)) & 1u);
            pvA[r] = fast_exp2(kA ? preA[r] : -1e30f);
            pvB[r] = fast_exp2(kB ? preB[r] : -1e30f);
        }
        Ps[p*4 + 0] = (uint_t)f16bits(pvA[0]) | ((uint_t)f16bits(pvA[1]) << 16);
        Ps[p*4 + 1] = (uint_t)f16bits(pvA[2]) | ((uint_t)f16bits(pvA[3]) << 16);
        Ps[p*4 + 2] = (uint_t)f16bits(pvB[0]) | ((uint_t)f16bits(pvB[1]) << 16);
        Ps[p*4 + 3] = (uint_t)f16bits(pvB[2]) | ((uint_t)f16bits(pvB[3]) << 16);
    }
    __syncthreads();   // all dpT reads done -> safe to overwrite with P

    // write P row-major over sBuf: P[o][t] at sBuf[o*PSTR + t]
    #pragma unroll
    for (int tt = 0; tt < 8; ++tt) {
        const int c = (wave * 8 + tt) * 16 + m;
        ushort_t* pp = &sBuf[quad * 4 * PSTR + c];
        const uint_t lo = Ps[2*tt], hi = Ps[2*tt + 1];
        pp[0]        = (ushort_t)lo;
        pp[PSTR]     = (ushort_t)(lo >> 16);
        pp[2*PSTR]   = (ushort_t)hi;
        pp[3*PSTR]   = (ushort_t)(hi >> 16);
    }
    __syncthreads();

    // ---------------- Phase C: PV + MFMA row sums ---------------------------
    const int d0 = (wave & 3) * 16;
    const int th = wave >> 2;
    f32x4 O  = {0.f, 0.f, 0.f, 0.f};
    f32x4 RS = {0.f, 0.f, 0.f, 0.f};
    half8 ONE;
    #pragma unroll
    for (int i = 0; i < 8; ++i) ONE[i] = (_Float16)1.0f;
    const ushort_t* ph_base = &sBuf[m * PSTR + th * 512 + quad * 8];
    const ushort_t* vv_base = vh + ((size_t)bh * 65536
                                    + (size_t)(th * 64 + quad) * 512
                                    + (size_t)(d0 + m) * 8);
    #pragma unroll 4
    for (int i = 0; i < 16; ++i) {
        half8 ph = *(const half8*)(ph_base + i * 32);
        half8 vv = *(const half8*)(vv_base + (size_t)i * 2048);
        O  = __builtin_amdgcn_mfma_f32_16x16x32_f16(ph, vv, O, 0, 0, 0);
        RS = __builtin_amdgcn_mfma_f32_16x16x32_f16(ph, ONE, RS, 0, 0, 0);
    }
    if (wave < 4) {
        #pragma unroll
        for (int r = 0; r < 4; ++r) oBuf[quad * 4 + r][d0 + m] = O[r];
    }
    if (wave == 0 && m == 0) {   // lanes 0,16,32,48: publish th=0 partials
        #pragma unroll
        for (int r = 0; r < 4; ++r) lsRow[quad * 4 + r] = RS[r];
    }
    __syncthreads();
    if (wave >= 4) {
        #pragma unroll
        for (int r = 0; r < 4; ++r) {
            const int br = quad * 4 + r;
            const int s = s0 - 1 + br;
            if (br >= 1 && br <= RPB && s < S_LEN) {
                const float lsum = lsRow[br] + RS[r];
                out[((size_t)bh * S_LEN + s) * D_DIM + d0 + m] =
                    (O[r] + oBuf[br][d0 + m]) / lsum;
            }
        }
    }
}

extern "C" void kernel_launch(void* const* d_in, const int* in_sizes, int n_in,
                              void* d_out, int out_size, void* d_ws, size_t ws_size,
                              hipStream_t stream) {
    const float* q      = (const float*)d_in[0];
    const float* k      = (const float*)d_in[1];
    const float* v      = (const float*)d_in[2];
    const int*   mask   = (const int*)d_in[3];
    const float* conv_w = (const float*)d_in[4];
    const float* conv_b = (const float*)d_in[5];
    const float* lin_w  = (const float*)d_in[6];
    const float* lin_b  = (const float*)d_in[7];
    float* out = (float*)d_out;

    char* wsb = (char*)d_ws;
    const size_t MB = 1024 * 1024;
    ushort_t* kh   = (ushort_t*)(wsb + 0 * MB);          // 2 MiB
    ushort_t* vh   = (ushort_t*)(wsb + 2 * MB);          // 2 MiB
    unsigned* mw   = (unsigned*)(wsb + 4 * MB);          // 256 KiB
    ushort_t* wtab = (ushort_t*)(wsb + 4 * MB + 256 * 1024);  // 12 KiB

    prep<<<dim3(1025), 256, 0, stream>>>(k, v, mask, conv_w, kh, vh, mw, wtab);
    fused_qk_conv_av<<<dim3(NSB, NBH), 512, 0, stream>>>(
        q, kh, mw, vh, wtab, conv_b, lin_w, lin_b, out);
}